// Round 4
// baseline (246.825 us; speedup 1.0000x reference)
//
#include <hip/hip_runtime.h>
#include <cmath>

#define DIM 128
#define NHALF 4096
#define NROWS 8192
#define NTILES 2080
// FRAG_SCALE^2 = log2(e)/tau = 1.4426950408889634/0.5
#define FRAG_SCALE 1.69864368f

typedef __attribute__((ext_vector_type(8))) short bf16x8;
typedef __attribute__((ext_vector_type(4))) float f32x4;

static __device__ __forceinline__ unsigned short f32_to_bf16(float f) {
  unsigned int u = __float_as_uint(f);
  u = (u + 0x7FFFu + ((u >> 16) & 1u)) >> 16;
  return (unsigned short)u;
}

static __device__ __forceinline__ void gl_lds16(const unsigned short* g,
                                                unsigned short* l) {
  __builtin_amdgcn_global_load_lds(
      (const __attribute__((address_space(1))) void*)g,
      (__attribute__((address_space(3))) void*)l, 16, 0, 0);
}

// One wave per pair r: normalize+scale -> bf16 rows r, r+4096; pos in fp32;
// zero rowsum and the tile-completion counter.
__global__ __launch_bounds__(256) void prep_kernel(
    const float* __restrict__ z_i, const float* __restrict__ z_j,
    unsigned short* __restrict__ A, float* __restrict__ rowsum,
    float* __restrict__ pos, unsigned int* __restrict__ counter) {
  int wave = threadIdx.x >> 6;
  int lane = threadIdx.x & 63;
  int r = blockIdx.x * 4 + wave;
  float2 a = *(const float2*)(z_i + (size_t)r * DIM + 2 * lane);
  float2 b = *(const float2*)(z_j + (size_t)r * DIM + 2 * lane);
  float sa = a.x * a.x + a.y * a.y;
  float sb = b.x * b.x + b.y * b.y;
  float dp = a.x * b.x + a.y * b.y;
#pragma unroll
  for (int off = 1; off < 64; off <<= 1) {
    sa += __shfl_xor(sa, off);
    sb += __shfl_xor(sb, off);
    dp += __shfl_xor(dp, off);
  }
  float na = fmaxf(sqrtf(sa), 1e-8f);
  float nb = fmaxf(sqrtf(sb), 1e-8f);
  float si = FRAG_SCALE / na;
  float sj = FRAG_SCALE / nb;
  unsigned int pa = (unsigned int)f32_to_bf16(a.x * si) |
                    ((unsigned int)f32_to_bf16(a.y * si) << 16);
  unsigned int pb = (unsigned int)f32_to_bf16(b.x * sj) |
                    ((unsigned int)f32_to_bf16(b.y * sj) << 16);
  ((unsigned int*)A)[(size_t)r * (DIM / 2) + lane] = pa;
  ((unsigned int*)A)[(size_t)(r + NHALF) * (DIM / 2) + lane] = pb;
  if (lane == 0) {
    float p = dp / (na * nb) * 2.0f;  // /tau, tau=0.5
    pos[r] = p;
    pos[r + NHALF] = p;
    rowsum[r] = 0.0f;
    rowsum[r + NHALF] = 0.0f;
    if (r == 0) *counter = 0u;
  }
}

// Upper-triangle 128x128 tiles. A/B staged to LDS via global_load_lds w=16
// (wave-uniform LDS base, HW places lane i at base + i*16B). LDS chunk c
// holds global (row=c>>4, cb=(c&15)^(row&7)) -> ds_read_b128 fragment reads
// spread 8 lanes per 4-bank group (the 1024B/wave floor, no hot banks).
// K-loop: 8 short-lived fragments per chunk, 16 MFMAs — no register blowup.
__global__ __launch_bounds__(256, 2) void simexp_kernel(
    const unsigned short* __restrict__ A, float* __restrict__ rowsum,
    const float* __restrict__ pos, unsigned int* __restrict__ counter,
    float* __restrict__ out) {
  __shared__ unsigned short lds[2 * 128 * 128];  // A tile then B tile, 64 KB
  const int tid = threadIdx.x;
  const int lane = tid & 63;
  const int w = tid >> 6;
  const int q = lane >> 4;
  const int n = lane & 15;

  // decode upper-triangle tile index t -> (bi, bj), bi <= bj, 64 blocks/side
  int t = blockIdx.x;
  int bi = (int)((129.0f - sqrtf(16641.0f - 8.0f * (float)t)) * 0.5f);
  int start = 64 * bi - (bi * (bi - 1)) / 2;
  if (t < start) {
    bi--;
    start = 64 * bi - (bi * (bi - 1)) / 2;
  } else if (t >= start + (64 - bi)) {
    start += 64 - bi;
    bi++;
  }
  int bj = bi + (t - start);

  const int rbBase = bi * 128;
  const int cbBase = bj * 128;
  const bool diag = (bi == bj);
  const int wrow = (w & 1) * 64;
  const int wcol = (w >> 1) * 64;

  const unsigned short* Ag = A + (size_t)rbBase * DIM;
  const unsigned short* Bg = A + (size_t)cbBase * DIM;
  unsigned short* ldsA = lds;
  unsigned short* ldsB = lds + 16384;

  // stage both tiles: 2048 16B-chunks each, wave w covers [w*512, w*512+512)
#pragma unroll
  for (int it = 0; it < 8; it++) {
    int cbase = w * 512 + it * 64;  // wave-uniform chunk base
    int c = cbase + lane;
    int row = c >> 4;
    int cb = (c & 15) ^ (row & 7);
    int off = __builtin_amdgcn_readfirstlane(cbase * 8);  // shorts
    gl_lds16(Ag + row * DIM + cb * 8, ldsA + off);
    gl_lds16(Bg + row * DIM + cb * 8, ldsB + off);
  }
  __syncthreads();

  f32x4 acc[16];
#pragma unroll
  for (int i = 0; i < 16; i++)
#pragma unroll
    for (int j = 0; j < 4; j++) acc[i][j] = 0.0f;

  const int s = n & 7;
#pragma unroll
  for (int kc = 0; kc < 4; kc++) {
    const int cbp = ((kc * 4 + q) ^ s) * 8;
    bf16x8 af[4], bfr[4];
#pragma unroll
    for (int mi = 0; mi < 4; mi++)
      af[mi] = *(const bf16x8*)&ldsA[(wrow + mi * 16 + n) * 128 + cbp];
#pragma unroll
    for (int ni = 0; ni < 4; ni++)
      bfr[ni] = *(const bf16x8*)&ldsB[(wcol + ni * 16 + n) * 128 + cbp];
#pragma unroll
    for (int mi = 0; mi < 4; mi++)
#pragma unroll
      for (int ni = 0; ni < 4; ni++)
        acc[mi * 4 + ni] = __builtin_amdgcn_mfma_f32_16x16x32_bf16(
            af[mi], bfr[ni], acc[mi * 4 + ni], 0, 0, 0);
  }

  // epilogue: exp2, diagonal mask, row + column accumulation
  float eaccR[16];
  float eaccC[4];
#pragma unroll
  for (int i = 0; i < 16; i++) eaccR[i] = 0.0f;
#pragma unroll
  for (int i = 0; i < 4; i++) eaccC[i] = 0.0f;
#pragma unroll
  for (int mi = 0; mi < 4; mi++) {
#pragma unroll
    for (int ni = 0; ni < 4; ni++) {
#pragma unroll
      for (int rg = 0; rg < 4; rg++) {
        float v = acc[mi * 4 + ni][rg];
        float e = __builtin_amdgcn_exp2f(v);
        int grow = rbBase + wrow + mi * 16 + q * 4 + rg;
        int gcol = cbBase + wcol + ni * 16 + n;
        e = (grow == gcol) ? 0.0f : e;
        eaccR[mi * 4 + rg] += e;
        eaccC[ni] += e;
      }
    }
  }
#pragma unroll
  for (int mi = 0; mi < 4; mi++) {
#pragma unroll
    for (int rg = 0; rg < 4; rg++) {
      float v = eaccR[mi * 4 + rg];
      v += __shfl_xor(v, 1);
      v += __shfl_xor(v, 2);
      v += __shfl_xor(v, 4);
      v += __shfl_xor(v, 8);
      if (n == 0)
        atomicAdd(&rowsum[rbBase + wrow + mi * 16 + q * 4 + rg], v);
    }
  }
  if (!diag) {
#pragma unroll
    for (int ni = 0; ni < 4; ni++) {
      float v = eaccC[ni];
      v += __shfl_xor(v, 16);
      v += __shfl_xor(v, 32);
      if (lane < 16) atomicAdd(&rowsum[cbBase + wcol + ni * 16 + n], v);
    }
  }

  // last-block finalize: loss = mean(log(rowsum) - pos)
  __threadfence();
  __shared__ unsigned int lastFlag;
  if (tid == 0) {
    unsigned int old = __hip_atomic_fetch_add(counter, 1u, __ATOMIC_ACQ_REL,
                                              __HIP_MEMORY_SCOPE_AGENT);
    lastFlag = (old == NTILES - 1) ? 1u : 0u;
  }
  __syncthreads();
  if (lastFlag) {
    float local = 0.0f;
    for (int r = tid; r < NROWS; r += 256) {
      float rs = __hip_atomic_load(&rowsum[r], __ATOMIC_RELAXED,
                                   __HIP_MEMORY_SCOPE_AGENT);
      local += __logf(rs) - pos[r];
    }
#pragma unroll
    for (int off = 1; off < 64; off <<= 1) local += __shfl_xor(local, off);
    __shared__ float wsum[4];
    if (lane == 0) wsum[w] = local;
    __syncthreads();
    if (tid == 0)
      out[0] = (wsum[0] + wsum[1] + wsum[2] + wsum[3]) * (1.0f / (float)NROWS);
  }
}

extern "C" void kernel_launch(void* const* d_in, const int* in_sizes, int n_in,
                              void* d_out, int out_size, void* d_ws,
                              size_t ws_size, hipStream_t stream) {
  const float* z_i = (const float*)d_in[0];
  const float* z_j = (const float*)d_in[1];
  float* out = (float*)d_out;

  unsigned short* A = (unsigned short*)d_ws;             // 2 MB bf16 matrix
  float* rowsum = (float*)((char*)d_ws + 2097152);       // 32 KB
  float* pos = (float*)((char*)d_ws + 2097152 + 32768);  // 32 KB
  unsigned int* counter = (unsigned int*)((char*)d_ws + 2097152 + 65536);

  prep_kernel<<<NHALF / 4, 256, 0, stream>>>(z_i, z_j, A, rowsum, pos, counter);
  simexp_kernel<<<NTILES, 256, 0, stream>>>(A, rowsum, pos, counter, out);
}

// Round 5
// 143.716 us; speedup vs baseline: 1.7174x; 1.7174x over previous
//
#include <hip/hip_runtime.h>
#include <cmath>

#define DIM 128
#define NHALF 4096
#define NROWS 8192
#define NSTRIPS 64
#define CHUNK 4
#define NBLOCKS 544  // sum_{i=0}^{63} ceil((64-i)/4)
#define NTILES 2080
#define LSTRIDE 136  // shorts per LDS row (128 + 8 pad -> 2-way conflicts only)
// FRAG_SCALE^2 = log2(e)/tau = 1.4426950408889634/0.5
#define FRAG_SCALE 1.69864368f

typedef __attribute__((ext_vector_type(8))) short bf16x8;
typedef __attribute__((ext_vector_type(4))) float f32x4;

static __device__ __forceinline__ unsigned short f32_to_bf16(float f) {
  unsigned int u = __float_as_uint(f);
  u = (u + 0x7FFFu + ((u >> 16) & 1u)) >> 16;
  return (unsigned short)u;
}

// One wave per pair r: normalize+scale -> bf16 rows r, r+4096; pos in fp32;
// zero rowsum and the tile-completion counter.
__global__ __launch_bounds__(256) void prep_kernel(
    const float* __restrict__ z_i, const float* __restrict__ z_j,
    unsigned short* __restrict__ A, float* __restrict__ rowsum,
    float* __restrict__ pos, unsigned int* __restrict__ counter) {
  int wave = threadIdx.x >> 6;
  int lane = threadIdx.x & 63;
  int r = blockIdx.x * 4 + wave;
  float2 a = *(const float2*)(z_i + (size_t)r * DIM + 2 * lane);
  float2 b = *(const float2*)(z_j + (size_t)r * DIM + 2 * lane);
  float sa = a.x * a.x + a.y * a.y;
  float sb = b.x * b.x + b.y * b.y;
  float dp = a.x * b.x + a.y * b.y;
#pragma unroll
  for (int off = 1; off < 64; off <<= 1) {
    sa += __shfl_xor(sa, off);
    sb += __shfl_xor(sb, off);
    dp += __shfl_xor(dp, off);
  }
  float na = fmaxf(sqrtf(sa), 1e-8f);
  float nb = fmaxf(sqrtf(sb), 1e-8f);
  float si = FRAG_SCALE / na;
  float sj = FRAG_SCALE / nb;
  unsigned int pa = (unsigned int)f32_to_bf16(a.x * si) |
                    ((unsigned int)f32_to_bf16(a.y * si) << 16);
  unsigned int pb = (unsigned int)f32_to_bf16(b.x * sj) |
                    ((unsigned int)f32_to_bf16(b.y * sj) << 16);
  ((unsigned int*)A)[(size_t)r * (DIM / 2) + lane] = pa;
  ((unsigned int*)A)[(size_t)(r + NHALF) * (DIM / 2) + lane] = pb;
  if (lane == 0) {
    float p = dp / (na * nb) * 2.0f;  // /tau, tau=0.5
    pos[r] = p;
    pos[r + NHALF] = p;
    rowsum[r] = 0.0f;
    rowsum[r + NHALF] = 0.0f;
    if (r == 0) *counter = 0u;
  }
}

// Strip-persistent triangle blocks: block owns a 128-row A-strip (staged once
// into padded LDS via plain ds_write_b128) and loops over up to CHUNK column
// tiles j >= i. B fragments load straight from global (A is 2 MB, L2-hot).
// Row-sum exp accumulators live in registers across the whole j-loop; one
// row-atomic set per block. Column credit (symmetry) per off-diagonal tile.
__global__ __launch_bounds__(256) void simexp_kernel(
    const unsigned short* __restrict__ Amat, float* __restrict__ rowsum,
    const float* __restrict__ pos, unsigned int* __restrict__ counter,
    float* __restrict__ out) {
  __shared__ unsigned short ldsA[128 * LSTRIDE];
  const int tid = threadIdx.x;
  const int lane = tid & 63;
  const int w = tid >> 6;
  const int q = lane >> 4;
  const int n = lane & 15;

  // decode block -> (strip i, first col tile j0); scalar, <=64 iterations
  int b = blockIdx.x;
  int i = 0;
  for (;;) {
    int nb = (NSTRIPS - i + CHUNK - 1) / CHUNK;
    if (b < nb) break;
    b -= nb;
    ++i;
  }
  const int j0 = i + b * CHUNK;
  const int rbBase = i * 128;
  const int wrow = (w & 1) * 64;
  const int wcol = (w >> 1) * 64;

  // stage the A strip: 128 rows x 128 shorts = 2048 16B chunks, 8/thread
  {
    const unsigned short* Ag = Amat + (size_t)rbBase * DIM;
#pragma unroll
    for (int it = 0; it < 8; it++) {
      int c = it * 256 + tid;
      int row = c >> 4;
      int cc = c & 15;
      *(uint4*)&ldsA[row * LSTRIDE + cc * 8] =
          *(const uint4*)(Ag + (size_t)row * DIM + cc * 8);
    }
  }
  __syncthreads();

  float eaccR[16];
#pragma unroll
  for (int x = 0; x < 16; x++) eaccR[x] = 0.0f;

#pragma unroll
  for (int jj = 0; jj < CHUNK; jj++) {
    const int j = j0 + jj;
    if (j >= NSTRIPS) break;
    const int cbBase = j * 128;
    const unsigned short* Bg = Amat + (size_t)(cbBase + wcol) * DIM;

    f32x4 acc[16];
#pragma unroll
    for (int kc = 0; kc < 4; kc++) {
      bf16x8 af[4], bfr[4];
#pragma unroll
      for (int ni = 0; ni < 4; ni++)
        bfr[ni] = *(const bf16x8*)(Bg + (size_t)(ni * 16 + n) * DIM + kc * 32 + q * 8);
#pragma unroll
      for (int mi = 0; mi < 4; mi++)
        af[mi] = *(const bf16x8*)&ldsA[(wrow + mi * 16 + n) * LSTRIDE + kc * 32 + q * 8];
      if (kc == 0) {
        const f32x4 z = {0.0f, 0.0f, 0.0f, 0.0f};
#pragma unroll
        for (int mi = 0; mi < 4; mi++)
#pragma unroll
          for (int ni = 0; ni < 4; ni++)
            acc[mi * 4 + ni] = __builtin_amdgcn_mfma_f32_16x16x32_bf16(
                af[mi], bfr[ni], z, 0, 0, 0);
      } else {
#pragma unroll
        for (int mi = 0; mi < 4; mi++)
#pragma unroll
          for (int ni = 0; ni < 4; ni++)
            acc[mi * 4 + ni] = __builtin_amdgcn_mfma_f32_16x16x32_bf16(
                af[mi], bfr[ni], acc[mi * 4 + ni], 0, 0, 0);
      }
    }

    if (j == i) {
      // diagonal tile: mask self-similarity, row credit only
#pragma unroll
      for (int mi = 0; mi < 4; mi++) {
#pragma unroll
        for (int ni = 0; ni < 4; ni++) {
#pragma unroll
          for (int rg = 0; rg < 4; rg++) {
            int lrow = wrow + mi * 16 + q * 4 + rg;
            int lcol = wcol + ni * 16 + n;
            float e = __builtin_amdgcn_exp2f(acc[mi * 4 + ni][rg]);
            eaccR[mi * 4 + rg] += (lrow == lcol) ? 0.0f : e;
          }
        }
      }
    } else {
      float eaccC[4] = {0.0f, 0.0f, 0.0f, 0.0f};
#pragma unroll
      for (int mi = 0; mi < 4; mi++) {
#pragma unroll
        for (int ni = 0; ni < 4; ni++) {
#pragma unroll
          for (int rg = 0; rg < 4; rg++) {
            float e = __builtin_amdgcn_exp2f(acc[mi * 4 + ni][rg]);
            eaccR[mi * 4 + rg] += e;
            eaccC[ni] += e;
          }
        }
      }
      // column credit: reduce over q, one atomic per column (lanes 0..15)
#pragma unroll
      for (int ni = 0; ni < 4; ni++) {
        float v = eaccC[ni];
        v += __shfl_xor(v, 16);
        v += __shfl_xor(v, 32);
        if (lane < 16) atomicAdd(&rowsum[cbBase + wcol + ni * 16 + n], v);
      }
    }
  }

  // row credit: reduce over n, one atomic per row, once per block
#pragma unroll
  for (int mi = 0; mi < 4; mi++) {
#pragma unroll
    for (int rg = 0; rg < 4; rg++) {
      float v = eaccR[mi * 4 + rg];
      v += __shfl_xor(v, 1);
      v += __shfl_xor(v, 2);
      v += __shfl_xor(v, 4);
      v += __shfl_xor(v, 8);
      if (n == 0)
        atomicAdd(&rowsum[rbBase + wrow + mi * 16 + q * 4 + rg], v);
    }
  }

  // last-block finalize: loss = mean(log(rowsum) - pos)
  __threadfence();
  __shared__ unsigned int lastFlag;
  if (tid == 0) {
    unsigned int old = __hip_atomic_fetch_add(counter, 1u, __ATOMIC_ACQ_REL,
                                              __HIP_MEMORY_SCOPE_AGENT);
    lastFlag = (old == NBLOCKS - 1) ? 1u : 0u;
  }
  __syncthreads();
  if (lastFlag) {
    float local = 0.0f;
    for (int r = tid; r < NROWS; r += 256) {
      float rs = __hip_atomic_load(&rowsum[r], __ATOMIC_RELAXED,
                                   __HIP_MEMORY_SCOPE_AGENT);
      local += __logf(rs) - pos[r];
    }
#pragma unroll
    for (int off = 1; off < 64; off <<= 1) local += __shfl_xor(local, off);
    __shared__ float wsum[4];
    if (lane == 0) wsum[w] = local;
    __syncthreads();
    if (tid == 0)
      out[0] = (wsum[0] + wsum[1] + wsum[2] + wsum[3]) * (1.0f / (float)NROWS);
  }
}

extern "C" void kernel_launch(void* const* d_in, const int* in_sizes, int n_in,
                              void* d_out, int out_size, void* d_ws,
                              size_t ws_size, hipStream_t stream) {
  const float* z_i = (const float*)d_in[0];
  const float* z_j = (const float*)d_in[1];
  float* out = (float*)d_out;

  unsigned short* A = (unsigned short*)d_ws;             // 2 MB bf16 matrix
  float* rowsum = (float*)((char*)d_ws + 2097152);       // 32 KB
  float* pos = (float*)((char*)d_ws + 2097152 + 32768);  // 32 KB
  unsigned int* counter = (unsigned int*)((char*)d_ws + 2097152 + 65536);

  prep_kernel<<<NHALF / 4, 256, 0, stream>>>(z_i, z_j, A, rowsum, pos, counter);
  simexp_kernel<<<NBLOCKS, 256, 0, stream>>>(A, rowsum, pos, counter, out);
}